// Round 7
// baseline (603.239 us; speedup 1.0000x reference)
//
#include <hip/hip_runtime.h>
#include <hip/hip_bf16.h>

#define B_ROWS   524288
#define MEL_BINS 128
#define DIM      64
#define KCODES   128

// ---------------- workspace layout (floats) ----------------
#define WS_WT  0                            // 8192  : W_in^T, WT[j*64+d]
#define WS_C0T (WS_WT + MEL_BINS*DIM)       // 8192  : cb0^T, c0T[d*128+k]
#define WS_C1T (WS_C0T + DIM*KCODES)        // 8192  : cb1^T
#define WS_N0  (WS_C1T + DIM*KCODES)        // 128
#define WS_N1  (WS_N0 + KCODES)             // 128
#define WS_T0  (WS_N1 + KCODES)             // 16384 : cb0 @ W_out^T
#define WS_T1  (WS_T0 + KCODES*MEL_BINS)    // 16384
#define WS_TOT (WS_T1 + KCODES*MEL_BINS)    // 57600 floats = 230400 B

// numpy pairwise_sum (scalar path) emulation for n=64 of v[d]*v[d].
__device__ __forceinline__ float np_pairwise64_sq(const float* v) {
#pragma clang fp contract(off)
    float r0 = v[0]*v[0], r1 = v[1]*v[1], r2 = v[2]*v[2], r3 = v[3]*v[3];
    float r4 = v[4]*v[4], r5 = v[5]*v[5], r6 = v[6]*v[6], r7 = v[7]*v[7];
#pragma unroll
    for (int i = 8; i < 64; i += 8) {
        r0 += v[i+0]*v[i+0]; r1 += v[i+1]*v[i+1];
        r2 += v[i+2]*v[i+2]; r3 += v[i+3]*v[i+3];
        r4 += v[i+4]*v[i+4]; r5 += v[i+5]*v[i+5];
        r6 += v[i+6]*v[i+6]; r7 += v[i+7]*v[i+7];
    }
    return ((r0 + r1) + (r2 + r3)) + ((r4 + r5) + (r6 + r7));
}

__global__ __launch_bounds__(256) void rvq_precomp(
    const float* __restrict__ W_in, const float* __restrict__ cb0,
    const float* __restrict__ cb1, const float* __restrict__ W_out,
    float* __restrict__ ws)
{
#pragma clang fp contract(off)
    float* WT  = ws + WS_WT;
    float* c0T = ws + WS_C0T;
    float* c1T = ws + WS_C1T;
    float* n0  = ws + WS_N0;
    float* n1  = ws + WS_N1;
    float* T0  = ws + WS_T0;
    float* T1  = ws + WS_T1;

    int tid = blockIdx.x * 256 + threadIdx.x;
    if (tid < 16384) {                       // T0[i][m] (mel path: loose threshold)
        int i = tid >> 7, m = tid & 127;
        double a = 0.0;
        for (int d = 0; d < DIM; ++d)
            a = fma((double)cb0[i*DIM + d], (double)W_out[m*DIM + d], a);
        T0[tid] = (float)a;
    } else if (tid < 32768) {                // T1[i][m]
        int t = tid - 16384;
        int i = t >> 7, m = t & 127;
        double a = 0.0;
        for (int d = 0; d < DIM; ++d)
            a = fma((double)cb1[i*DIM + d], (double)W_out[m*DIM + d], a);
        T1[t] = (float)a;
    } else if (tid < 40960) {                // WT[j][d] = W_in[d][j]
        int t = tid - 32768;
        int j = t >> 6, d = t & 63;
        WT[t] = W_in[d*MEL_BINS + j];
    } else if (tid < 41216) {                // n0 / n1 (exact np pairwise)
        int t = tid - 40960;
        const float* cb = (t & 128) ? cb1 : cb0;
        float*       nn = (t & 128) ? n1  : n0;
        int k = t & 127;
        nn[k] = np_pairwise64_sq(cb + k*DIM);
    } else if (tid < 49408) {                // c0T[d][k] = cb0[k][d]
        int t = tid - 41216;
        int d = t >> 7, k = t & 127;
        c0T[t] = cb0[k*DIM + d];
    } else if (tid < 57600) {                // c1T[d][k] = cb1[k][d]
        int t = tid - 49408;
        int d = t >> 7, k = t & 127;
        c1T[t] = cb1[k*DIM + d];
    }
}

// 1 row/thread. Argmin loops restructured for ILP: 16 independent ascending-d
// accumulator chains per k-chunk (transposed codebook, wave-uniform s_loads).
// PER-K FP OP ORDER IS BIT-IDENTICAL to the R3-verified np-f32 emulation.
__global__ __launch_bounds__(256) void rvq_main(
    const float* __restrict__ mel,
    const float* __restrict__ b_in,
    const float* __restrict__ cb0,
    const float* __restrict__ cb1,
    const float* __restrict__ b_out,
    const float* __restrict__ ws,
    float* __restrict__ out_mel,
    float* __restrict__ out_idx)
{
#pragma clang fp contract(off)
    const float* __restrict__ WT  = ws + WS_WT;
    const float* __restrict__ c0T = ws + WS_C0T;
    const float* __restrict__ c1T = ws + WS_C1T;
    const float* __restrict__ n0  = ws + WS_N0;
    const float* __restrict__ n1  = ws + WS_N1;
    const float* __restrict__ T0  = ws + WS_T0;
    const float* __restrict__ T1  = ws + WS_T1;

    const int b = blockIdx.x * 256 + threadIdx.x;

    // ---- z = mel @ W_in^T : ascending-j fmaf chain per d (frozen order)
    float z[DIM];
#pragma unroll
    for (int d = 0; d < DIM; ++d) z[d] = 0.f;

    const float4* melr = reinterpret_cast<const float4*>(mel + (size_t)b * MEL_BINS);
    for (int jc = 0; jc < MEL_BINS / 4; ++jc) {
        float4 m4 = melr[jc];
        const float* w = WT + jc * 4 * DIM;    // wave-uniform -> scalar loads
#pragma unroll
        for (int d = 0; d < DIM; ++d) z[d] = fmaf(w[d],         m4.x, z[d]);
#pragma unroll
        for (int d = 0; d < DIM; ++d) z[d] = fmaf(w[DIM + d],   m4.y, z[d]);
#pragma unroll
        for (int d = 0; d < DIM; ++d) z[d] = fmaf(w[2*DIM + d], m4.z, z[d]);
#pragma unroll
        for (int d = 0; d < DIM; ++d) z[d] = fmaf(w[3*DIM + d], m4.w, z[d]);
    }
#pragma unroll
    for (int d = 0; d < DIM; ++d) z[d] = z[d] + b_in[d];

    // ================= codebook 0 =================
    float s0 = z[0]*z[0], s1 = z[1]*z[1], s2 = z[2]*z[2], s3 = z[3]*z[3];
    float s4 = z[4]*z[4], s5 = z[5]*z[5], s6 = z[6]*z[6], s7 = z[7]*z[7];
#pragma unroll
    for (int i = 8; i < 64; i += 8) {
        s0 += z[i+0]*z[i+0]; s1 += z[i+1]*z[i+1];
        s2 += z[i+2]*z[i+2]; s3 += z[i+3]*z[i+3];
        s4 += z[i+4]*z[i+4]; s5 += z[i+5]*z[i+5];
        s6 += z[i+6]*z[i+6]; s7 += z[i+7]*z[i+7];
    }
    float sum_rr = ((s0 + s1) + (s2 + s3)) + ((s4 + s5) + (s6 + s7));

    float best0 = 3.4e38f; int i0 = 0;
    for (int kc = 0; kc < KCODES; kc += 16) {
        float acc[16];
#pragma unroll
        for (int t = 0; t < 16; ++t) acc[t] = 0.f;
#pragma unroll 4
        for (int d = 0; d < DIM; ++d) {
            const float* row = c0T + d * KCODES + kc;  // wave-uniform, 64 B
            float zd = z[d];
#pragma unroll
            for (int t = 0; t < 16; ++t) acc[t] = fmaf(row[t], zd, acc[t]);
        }
#pragma unroll
        for (int t = 0; t < 16; ++t) {
            float dist = (sum_rr - 2.0f*acc[t]) + n0[kc + t];
            if (dist < best0) { best0 = dist; i0 = kc + t; }  // ascending k, strict <
        }
    }

    // residual = r - code : elementwise rounded sub
    {
        const float* c = cb0 + (size_t)i0 * DIM;
#pragma unroll
        for (int d = 0; d < DIM; ++d) z[d] = z[d] - c[d];
    }

    // ================= codebook 1 =================
    s0 = z[0]*z[0]; s1 = z[1]*z[1]; s2 = z[2]*z[2]; s3 = z[3]*z[3];
    s4 = z[4]*z[4]; s5 = z[5]*z[5]; s6 = z[6]*z[6]; s7 = z[7]*z[7];
#pragma unroll
    for (int i = 8; i < 64; i += 8) {
        s0 += z[i+0]*z[i+0]; s1 += z[i+1]*z[i+1];
        s2 += z[i+2]*z[i+2]; s3 += z[i+3]*z[i+3];
        s4 += z[i+4]*z[i+4]; s5 += z[i+5]*z[i+5];
        s6 += z[i+6]*z[i+6]; s7 += z[i+7]*z[i+7];
    }
    sum_rr = ((s0 + s1) + (s2 + s3)) + ((s4 + s5) + (s6 + s7));

    float best1 = 3.4e38f; int i1 = 0;
    for (int kc = 0; kc < KCODES; kc += 16) {
        float acc[16];
#pragma unroll
        for (int t = 0; t < 16; ++t) acc[t] = 0.f;
#pragma unroll 4
        for (int d = 0; d < DIM; ++d) {
            const float* row = c1T + d * KCODES + kc;
            float zd = z[d];
#pragma unroll
            for (int t = 0; t < 16; ++t) acc[t] = fmaf(row[t], zd, acc[t]);
        }
#pragma unroll
        for (int t = 0; t < 16; ++t) {
            float dist = (sum_rr - 2.0f*acc[t]) + n1[kc + t];
            if (dist < best1) { best1 = dist; i1 = kc + t; }
        }
    }

    // ---- decode: out = T0[i0] + T1[i1] + b_out
    const float4* t0r = reinterpret_cast<const float4*>(T0 + (size_t)i0 * MEL_BINS);
    const float4* t1r = reinterpret_cast<const float4*>(T1 + (size_t)i1 * MEL_BINS);
    float4* outr = reinterpret_cast<float4*>(out_mel + (size_t)b * MEL_BINS);
#pragma unroll 4
    for (int q = 0; q < MEL_BINS / 4; ++q) {
        float4 a = t0r[q], c = t1r[q];
        float4 o;
        o.x = a.x + c.x + b_out[4*q + 0];
        o.y = a.y + c.y + b_out[4*q + 1];
        o.z = a.z + c.z + b_out[4*q + 2];
        o.w = a.w + c.w + b_out[4*q + 3];
        outr[q] = o;
    }

    out_idx[2*(size_t)b + 0] = (float)i0;
    out_idx[2*(size_t)b + 1] = (float)i1;
}

extern "C" void kernel_launch(void* const* d_in, const int* in_sizes, int n_in,
                              void* d_out, int out_size, void* d_ws, size_t ws_size,
                              hipStream_t stream)
{
    const float* mel   = (const float*)d_in[0];
    const float* W_in  = (const float*)d_in[1];
    const float* b_in  = (const float*)d_in[2];
    const float* cb0   = (const float*)d_in[3];
    const float* cb1   = (const float*)d_in[4];
    const float* W_out = (const float*)d_in[5];
    const float* b_out = (const float*)d_in[6];

    float* ws      = (float*)d_ws;                // 230400 bytes used
    float* out_mel = (float*)d_out;
    float* out_idx = (float*)d_out + (size_t)B_ROWS * MEL_BINS;

    rvq_precomp<<<(WS_TOT + 255) / 256, 256, 0, stream>>>(W_in, cb0, cb1, W_out, ws);
    rvq_main<<<B_ROWS / 256, 256, 0, stream>>>(mel, b_in, cb0, cb1, b_out, ws,
                                               out_mel, out_idx);
}